// Round 17
// baseline (415.154 us; speedup 1.0000x reference)
//
#include <hip/hip_runtime.h>
#include <hip/hip_bf16.h>
#include <math.h>

#define N_NODES 5000
#define N_ELEMS 10
#define C_DIM   128
#define N_EDGE  100000
#define N_BES   8
#define RAD_H   64
#define NL      4
#define SH_DIM  16
#define ONODES  8
#define TPW_ROWS 64
#define AS_LD   (RAD_H + 4)

// scales
#define SC_SCALE 0.02795084971874737f    // 1/sqrt(128*10)
#define X_SCALE  0.08838834764831845f    // 1/sqrt(128)
#define R1_SCALE 0.3535533905932738f     // 1/sqrt(8)
#define R_SCALE  0.125f                  // 1/sqrt(64)
#define OUT_SCALE 0.004419417382415922f  // (1/sqrt(128))/20

__device__ __forceinline__ float silu(float v) { return v / (1.f + __expf(-v)); }
__device__ __forceinline__ unsigned short bf16bits(float v) {
    __hip_bfloat16 h = __float2bfloat16(v);
    return *(unsigned short*)&h;
}

// ---------------- node kernel: sc + x ----------------
__global__ __launch_bounds__(128) void node_kernel(
    const float* __restrict__ node_attrs, const float* __restrict__ node_feats,
    const float* __restrict__ w_skip, const float* __restrict__ w_up,
    float* __restrict__ x, float* __restrict__ sc_out)
{
    int n = blockIdx.x, t = threadIdx.x;
    __shared__ float f[C_DIM];
    __shared__ float at[N_ELEMS];
    f[t] = node_feats[(size_t)n * C_DIM + t];
    if (t < N_ELEMS) at[t] = node_attrs[(size_t)n * N_ELEMS + t];
    __syncthreads();

    float acc = 0.f;
    for (int a = 0; a < N_ELEMS; ++a) {
        float av = at[a];
        if (av != 0.f) {
            const float* wp = w_skip + a * C_DIM + t;
            float s2 = 0.f;
            #pragma unroll 8
            for (int c = 0; c < C_DIM; ++c) s2 += f[c] * wp[(size_t)c * (N_ELEMS * C_DIM)];
            acc += av * s2;
        }
    }
    sc_out[(size_t)n * C_DIM + t] = acc * SC_SCALE;

    float xa = 0.f;
    #pragma unroll 8
    for (int k = 0; k < C_DIM; ++k) xa += f[k] * w_up[k * C_DIM + t];
    x[(size_t)n * C_DIM + t] = xa * X_SCALE;
}

// ---------------- radial MLP layers 1-3 -> h3 ----------------
__global__ __launch_bounds__(256) void radial_kernel(
    const float* __restrict__ edge_feats,
    const float* __restrict__ w1, const float* __restrict__ w2, const float* __restrict__ w3,
    float* __restrict__ h3out)
{
    __shared__ float w1s[N_BES * RAD_H];
    __shared__ float w2s[RAD_H * RAD_H];
    __shared__ float w3s[RAD_H * RAD_H];
    __shared__ float h1s[4][RAD_H];
    __shared__ float h2s[4][RAD_H];
    int t = threadIdx.x;
    for (int i = t; i < N_BES * RAD_H; i += 256) w1s[i] = w1[i];
    for (int i = t; i < RAD_H * RAD_H; i += 256) { w2s[i] = w2[i]; w3s[i] = w3[i]; }
    __syncthreads();
    int sub = t >> 6, j = t & 63;
    for (int e0 = blockIdx.x * 4; e0 < N_EDGE; e0 += gridDim.x * 4) {
        int e = e0 + sub;
        if (e < N_EDGE) {
            const float4* ef = (const float4*)(edge_feats + (size_t)e * N_BES);
            float4 f0 = ef[0], f1 = ef[1];
            float a = f0.x * w1s[0 * RAD_H + j] + f0.y * w1s[1 * RAD_H + j]
                    + f0.z * w1s[2 * RAD_H + j] + f0.w * w1s[3 * RAD_H + j]
                    + f1.x * w1s[4 * RAD_H + j] + f1.y * w1s[5 * RAD_H + j]
                    + f1.z * w1s[6 * RAD_H + j] + f1.w * w1s[7 * RAD_H + j];
            h1s[sub][j] = silu(a * R1_SCALE);
        }
        __syncthreads();
        if (e < N_EDGE) {
            const float4* h4 = (const float4*)h1s[sub];
            float a = 0.f;
            #pragma unroll
            for (int kk = 0; kk < RAD_H / 4; ++kk) {
                float4 h = h4[kk];
                int k = kk * 4;
                a += h.x * w2s[(k + 0) * RAD_H + j] + h.y * w2s[(k + 1) * RAD_H + j]
                   + h.z * w2s[(k + 2) * RAD_H + j] + h.w * w2s[(k + 3) * RAD_H + j];
            }
            h2s[sub][j] = silu(a * R_SCALE);
        }
        __syncthreads();
        if (e < N_EDGE) {
            const float4* h4 = (const float4*)h2s[sub];
            float a = 0.f;
            #pragma unroll
            for (int kk = 0; kk < RAD_H / 4; ++kk) {
                float4 h = h4[kk];
                int k = kk * 4;
                a += h.x * w3s[(k + 0) * RAD_H + j] + h.y * w3s[(k + 1) * RAD_H + j]
                   + h.z * w3s[(k + 2) * RAD_H + j] + h.w * w3s[(k + 3) * RAD_H + j];
            }
            h3out[(size_t)e * RAD_H + j] = silu(a * R_SCALE);
        }
        __syncthreads();
    }
}

// ---------------- CSR build ----------------
__global__ void hist_kernel(const int* __restrict__ recv, int* __restrict__ deg)
{
    int e = blockIdx.x * 256 + threadIdx.x;
    if (e < N_EDGE) atomicAdd(&deg[recv[e]], 1);
}

__global__ __launch_bounds__(256) void scan_kernel(const int* __restrict__ deg, int* __restrict__ offs)
{
    __shared__ int sums[256];
    int t = threadIdx.x;
    int base = t * 20;
    int loc[20]; int s = 0;
    #pragma unroll
    for (int i = 0; i < 20; ++i) { int idx = base + i; int v = (idx < N_NODES) ? deg[idx] : 0; loc[i] = s; s += v; }
    sums[t] = s; __syncthreads();
    for (int off = 1; off < 256; off <<= 1) {
        int v = (t >= off) ? sums[t - off] : 0;
        __syncthreads();
        sums[t] += v;
        __syncthreads();
    }
    int ex = (t == 0) ? 0 : sums[t - 1];
    #pragma unroll
    for (int i = 0; i < 20; ++i) { int idx = base + i; if (idx < N_NODES) offs[idx] = ex + loc[i]; }
    if (t == 255) offs[N_NODES] = sums[255];
}

__global__ void scatter_kernel(const int* __restrict__ recv, const int* __restrict__ offs,
                               int* __restrict__ cursor, int* __restrict__ perm)
{
    int e = blockIdx.x * 256 + threadIdx.x;
    if (e < N_EDGE) {
        int r = recv[e];
        int pos = atomicAdd(&cursor[r], 1);
        perm[offs[r] + pos] = e;
    }
}

// ---------------- reorder: sid_arr[idx]=sender[perm[idx]], ea_perm[idx]=edge_attrs[perm[idx]] ----------------
__global__ void reorder_kernel(const int* __restrict__ perm, const int* __restrict__ sender,
                               const float* __restrict__ edge_attrs,
                               int* __restrict__ sid_arr, float4* __restrict__ ea_perm4)
{
    int idx = blockIdx.x * 256 + threadIdx.x;
    if (idx < N_EDGE) {
        int e = perm[idx];
        sid_arr[idx] = sender[e];
        const float4* src = (const float4*)(edge_attrs + (size_t)e * SH_DIM);
        float4* dst = ea_perm4 + (size_t)idx * 4;
        dst[0] = src[0]; dst[1] = src[1]; dst[2] = src[2]; dst[3] = src[3];
    }
}

// ---------------- tpw GEMM (bf16 out): tpw[i,:] = h3[perm[i],:] @ w4*R_SCALE ----------------
// v2: 512 threads, 4x4 register tile/thread, same 49KB LDS -> 16 waves/CU
// (round-16: 256 thr = 8 waves/CU = 2/SIMD, occupancy 23%, LDS-latency-bound)
__global__ __launch_bounds__(512, 4) void tpw_gemm_kernel(
    const int* __restrict__ perm, const float* __restrict__ h3,
    const float* __restrict__ w4, __hip_bfloat16* __restrict__ tpw)
{
    int l = blockIdx.y, t = threadIdx.x;
    __shared__ float Bs[RAD_H * C_DIM];      // 32 KB
    __shared__ float As[TPW_ROWS * AS_LD];   // 17 KB (padded rows)
    for (int i = t; i < RAD_H * C_DIM; i += 512) {
        int k = i >> 7, c = i & 127;
        Bs[i] = w4[k * (NL * C_DIM) + l * C_DIM + c] * R_SCALE;
    }
    int tx = t & 31, ty = t >> 5;            // cols tx*4..+3, rows ty*4..+3 (ty in 0..15)
    int c0 = tx * 4;
    const int ntiles = (N_EDGE + TPW_ROWS - 1) / TPW_ROWS;
    for (int tile = blockIdx.x; tile < ntiles; tile += gridDim.x) {
        int i0 = tile * TPW_ROWS;
        __syncthreads();                     // B staged (first iter) / As readers done (later)
        {
            int r = t >> 3, q = t & 7;       // 8 threads/row, 2 float4 each
            int i = i0 + r;
            int e = perm[min(i, N_EDGE - 1)];
            const float4* src = (const float4*)(h3 + (size_t)e * RAD_H);
            float* dstrow = As + r * AS_LD;
            *(float4*)(dstrow + q * 8)     = src[q * 2];
            *(float4*)(dstrow + q * 8 + 4) = src[q * 2 + 1];
        }
        __syncthreads();
        float acc[4][4] = {};
        #pragma unroll 2
        for (int k0 = 0; k0 < RAD_H; k0 += 4) {
            float4 b0 = *(const float4*)&Bs[(k0 + 0) * C_DIM + c0];
            float4 b1 = *(const float4*)&Bs[(k0 + 1) * C_DIM + c0];
            float4 b2 = *(const float4*)&Bs[(k0 + 2) * C_DIM + c0];
            float4 b3 = *(const float4*)&Bs[(k0 + 3) * C_DIM + c0];
            #pragma unroll
            for (int rr = 0; rr < 4; ++rr) {
                float4 a = *(const float4*)&As[(ty * 4 + rr) * AS_LD + k0];
                acc[rr][0] += a.x * b0.x + a.y * b1.x + a.z * b2.x + a.w * b3.x;
                acc[rr][1] += a.x * b0.y + a.y * b1.y + a.z * b2.y + a.w * b3.y;
                acc[rr][2] += a.x * b0.z + a.y * b1.z + a.z * b2.z + a.w * b3.z;
                acc[rr][3] += a.x * b0.w + a.y * b1.w + a.z * b2.w + a.w * b3.w;
            }
        }
        #pragma unroll
        for (int rr = 0; rr < 4; ++rr) {
            int i = i0 + ty * 4 + rr;
            if (i < N_EDGE) {
                ushort4 pk;
                pk.x = bf16bits(acc[rr][0]);
                pk.y = bf16bits(acc[rr][1]);
                pk.z = bf16bits(acc[rr][2]);
                pk.w = bf16bits(acc[rr][3]);
                *(ushort4*)(tpw + (size_t)i * (NL * C_DIM) + l * C_DIM + c0) = pk;
            }
        }
    }
}

// ---------------- stream gather v3: 256 thr (l=t>>6 wave-uniform, 2 c's/thread) ----------------
__global__ __launch_bounds__(256, 4) void stream_gather_kernel(
    const int* __restrict__ offs, const int* __restrict__ sid_arr,
    const float* __restrict__ x, const float* __restrict__ ea_perm,
    const __hip_bfloat16* __restrict__ tpw, float* __restrict__ msg)
{
    int n = blockIdx.x, t = threadIdx.x;
    int cq = t & 63, l = t >> 6;          // l wave-uniform; c = cq*2, cq*2+1
    int c0 = cq * 2;
    float acc[7][2] = {};
    int nm = 2 * l + 1;
    int start = offs[n], end = offs[n + 1];

    for (int base = start; base < end; base += 4) {
        int idxb[4], sidb[4];
        #pragma unroll
        for (int j = 0; j < 4; ++j) idxb[j] = min(base + j, end - 1);
        #pragma unroll
        for (int j = 0; j < 4; ++j) sidb[j] = sid_arr[idxb[j]];   // wave-uniform -> s_load

        unsigned int tpb[4];
        float2 xv[4];
        #pragma unroll
        for (int j = 0; j < 4; ++j)
            tpb[j] = *(const unsigned int*)((const unsigned short*)tpw + (size_t)idxb[j] * (NL * C_DIM) + l * C_DIM + c0);
        #pragma unroll
        for (int j = 0; j < 4; ++j)
            xv[j] = *(const float2*)(x + (size_t)sidb[j] * C_DIM + c0);
        asm volatile("" : "+v"(tpb[0]), "+v"(tpb[1]), "+v"(tpb[2]), "+v"(tpb[3]),
                          "+v"(xv[0].x), "+v"(xv[0].y), "+v"(xv[1].x), "+v"(xv[1].y),
                          "+v"(xv[2].x), "+v"(xv[2].y), "+v"(xv[3].x), "+v"(xv[3].y));

        #pragma unroll
        for (int j = 0; j < 4; ++j) {
            unsigned int lo = (tpb[j] & 0xFFFFu) << 16;
            unsigned int hi = tpb[j] & 0xFFFF0000u;
            float tp0 = __uint_as_float(lo);
            float tp1 = __uint_as_float(hi);
            bool valid = (base + j < end);
            float xt0 = valid ? tp0 * xv[j].x : 0.f;
            float xt1 = valid ? tp1 * xv[j].y : 0.f;
            const float* ear = ea_perm + (size_t)idxb[j] * SH_DIM + l * l;   // wave-uniform
            #pragma unroll
            for (int m = 0; m < 7; ++m)
                if (m < nm) { acc[m][0] += ear[m] * xt0; acc[m][1] += ear[m] * xt1; }
        }
    }
    float* mout = msg + (size_t)n * (SH_DIM * C_DIM) + (size_t)(l * l) * C_DIM + c0;
    #pragma unroll
    for (int m = 0; m < 7; ++m)
        if (m < nm) *(float2*)(mout + (size_t)m * C_DIM) = make_float2(acc[m][0], acc[m][1]);
}

// ---------------- fallback fused gather (round-7, e-indexed) ----------------
__global__ __launch_bounds__(512, 4) void fused_gather_kernel(
    const int* __restrict__ perm, const int* __restrict__ offs,
    const int* __restrict__ sender, const float* __restrict__ x,
    const float* __restrict__ edge_attrs, const float* __restrict__ h3,
    const float* __restrict__ w4, float* __restrict__ msg)
{
    int n = blockIdx.x, t = threadIdx.x;
    int c = t & 127, l = t >> 7;
    float wc[RAD_H];
    #pragma unroll
    for (int k = 0; k < RAD_H; ++k)
        wc[k] = w4[k * (NL * C_DIM) + l * C_DIM + c];

    float acc[7] = {0.f, 0.f, 0.f, 0.f, 0.f, 0.f, 0.f};
    int nm = 2 * l + 1;
    int start = offs[n], end = offs[n + 1];
    if (start < end) {
        int e = __builtin_amdgcn_readfirstlane(perm[start]);
        int s = __builtin_amdgcn_readfirstlane(sender[e]);
        for (int idx = start; idx < end; ++idx) {
            #pragma unroll
            for (int k = 0; k < RAD_H; k += 8)
                asm volatile("" : "+v"(wc[k]), "+v"(wc[k+1]), "+v"(wc[k+2]), "+v"(wc[k+3]),
                                  "+v"(wc[k+4]), "+v"(wc[k+5]), "+v"(wc[k+6]), "+v"(wc[k+7]));
            int e_cur = e, s_cur = s;
            if (idx + 1 < end) {
                e = __builtin_amdgcn_readfirstlane(perm[idx + 1]);
                s = __builtin_amdgcn_readfirstlane(sender[e]);
            }
            const float* h3r = h3 + (size_t)e_cur * RAD_H;
            float xv = x[(size_t)s_cur * C_DIM + c];
            float tp0 = 0.f, tp1 = 0.f, tp2 = 0.f, tp3 = 0.f;
            #pragma unroll
            for (int q = 0; q < RAD_H / 4; ++q) {
                tp0 += h3r[4 * q + 0] * wc[4 * q + 0];
                tp1 += h3r[4 * q + 1] * wc[4 * q + 1];
                tp2 += h3r[4 * q + 2] * wc[4 * q + 2];
                tp3 += h3r[4 * q + 3] * wc[4 * q + 3];
            }
            float tp = (tp0 + tp1) + (tp2 + tp3);
            float xt = xv * (tp * R_SCALE);
            const float* ear = edge_attrs + (size_t)e_cur * SH_DIM + l * l;
            #pragma unroll
            for (int j = 0; j < 7; ++j)
                if (j < nm) acc[j] += ear[j] * xt;
        }
    }
    float* mout = msg + (size_t)n * (SH_DIM * C_DIM) + (size_t)(l * l) * C_DIM + c;
    #pragma unroll
    for (int j = 0; j < 7; ++j)
        if (j < nm) mout[(size_t)j * C_DIM] = acc[j];
}

// ---------------- out[n,m,d] = sum_c msg[n,m,c]*w_out[l(m),c,d]  (in place on d_out) ----------------
__global__ __launch_bounds__(256, 4) void out_kernel(
    float* __restrict__ out, const float* __restrict__ w_out)
{
    __shared__ float wlds[64 * C_DIM];        // 32 KB half-k panel
    int nb = blockIdx.x * ONODES, t = threadIdx.x;
    int dq = t & 31, rg = t >> 5;
    int d0 = dq * 4;
    #pragma unroll
    for (int l = 0; l < 4; ++l) {
        const int ms = l * l, cnt = 2 * l + 1;
        const int ntiles = ONODES * cnt / 4;  // 2,6,10,14
        float acc[2][4][4] = {};
        #pragma unroll
        for (int half = 0; half < 2; ++half) {
            const int k0h = half * 64;
            __syncthreads();
            {
                const float4* src = (const float4*)(w_out + ((size_t)l * C_DIM + k0h) * C_DIM);
                float4* dst = (float4*)wlds;
                for (int i = t; i < 64 * C_DIM / 4; i += 256) dst[i] = src[i];
            }
            __syncthreads();
            #pragma unroll
            for (int slot = 0; slot < 2; ++slot) {
                int ti = rg + slot * 8;
                if (ti < ntiles) {
                    int r0 = ti * 4;
                    const float* mrow[4];
                    #pragma unroll
                    for (int i = 0; i < 4; ++i) {
                        int r = r0 + i;
                        int node = r / cnt, mm = ms + r % cnt;
                        mrow[i] = out + ((size_t)(nb + node) * SH_DIM + mm) * C_DIM + k0h;
                    }
                    #pragma unroll 2
                    for (int k0 = 0; k0 < 64; k0 += 4) {
                        float4 b0 = *(const float4*)&wlds[(k0 + 0) * C_DIM + d0];
                        float4 b1 = *(const float4*)&wlds[(k0 + 1) * C_DIM + d0];
                        float4 b2 = *(const float4*)&wlds[(k0 + 2) * C_DIM + d0];
                        float4 b3 = *(const float4*)&wlds[(k0 + 3) * C_DIM + d0];
                        #pragma unroll
                        for (int i = 0; i < 4; ++i) {
                            float4 a = *(const float4*)(mrow[i] + k0);
                            acc[slot][i][0] += a.x * b0.x + a.y * b1.x + a.z * b2.x + a.w * b3.x;
                            acc[slot][i][1] += a.x * b0.y + a.y * b1.y + a.z * b2.y + a.w * b3.y;
                            acc[slot][i][2] += a.x * b0.z + a.y * b1.z + a.z * b2.z + a.w * b3.z;
                            acc[slot][i][3] += a.x * b0.w + a.y * b1.w + a.z * b2.w + a.w * b3.w;
                        }
                    }
                }
            }
        }
        #pragma unroll
        for (int slot = 0; slot < 2; ++slot) {
            int ti = rg + slot * 8;
            if (ti < ntiles) {
                int r0 = ti * 4;
                #pragma unroll
                for (int i = 0; i < 4; ++i) {
                    int r = r0 + i;
                    int node = r / cnt, mm = ms + r % cnt;
                    float4 r4 = make_float4(acc[slot][i][0] * OUT_SCALE, acc[slot][i][1] * OUT_SCALE,
                                            acc[slot][i][2] * OUT_SCALE, acc[slot][i][3] * OUT_SCALE);
                    *(float4*)(out + ((size_t)(nb + node) * SH_DIM + mm) * C_DIM + d0) = r4;
                }
            }
        }
    }
}

extern "C" void kernel_launch(void* const* d_in, const int* in_sizes, int n_in,
                              void* d_out, int out_size, void* d_ws, size_t ws_size,
                              hipStream_t stream)
{
    const float* node_attrs = (const float*)d_in[0];
    const float* node_feats = (const float*)d_in[1];
    const float* edge_attrs = (const float*)d_in[2];
    const float* edge_feats = (const float*)d_in[3];
    const int*   edge_index = (const int*)d_in[4];
    const float* w_up   = (const float*)d_in[5];
    const float* w_rad1 = (const float*)d_in[6];
    const float* w_rad2 = (const float*)d_in[7];
    const float* w_rad3 = (const float*)d_in[8];
    const float* w_rad4 = (const float*)d_in[9];
    const float* w_skip = (const float*)d_in[10];
    const float* w_out  = (const float*)d_in[11];
    const int* sender = edge_index;
    const int* recv   = edge_index + N_EDGE;

    float* out = (float*)d_out;                                 // msg staged here, then in-place
    float* sc  = out + (size_t)N_NODES * SH_DIM * C_DIM;

    // workspace layout (ws >= 233.4 MB proven; this needs ~138 MB)
    float* x   = (float*)d_ws;
    float* h3  = x + (size_t)N_NODES * C_DIM;
    int* deg    = (int*)(h3 + (size_t)N_EDGE * RAD_H);
    int* cursor = deg + 5120;
    int* offs   = cursor + 5120;
    int* perm   = offs + 5124;
    __hip_bfloat16* tpw = (__hip_bfloat16*)(perm + N_EDGE);
    int* sid_arr = (int*)(tpw + (size_t)N_EDGE * NL * C_DIM);
    float* ea_perm = (float*)(sid_arr + N_EDGE);
    size_t need = (size_t)((char*)(ea_perm + (size_t)N_EDGE * SH_DIM) - (char*)d_ws);
    int mode = (ws_size >= need) ? 1 : 0;

    hipMemsetAsync(deg, 0, 2 * 5120 * sizeof(int), stream);

    node_kernel<<<N_NODES, 128, 0, stream>>>(node_attrs, node_feats, w_skip, w_up, x, sc);
    radial_kernel<<<1024, 256, 0, stream>>>(edge_feats, w_rad1, w_rad2, w_rad3, h3);

    hist_kernel<<<(N_EDGE + 255) / 256, 256, 0, stream>>>(recv, deg);
    scan_kernel<<<1, 256, 0, stream>>>(deg, offs);
    scatter_kernel<<<(N_EDGE + 255) / 256, 256, 0, stream>>>(recv, offs, cursor, perm);

    if (mode == 1) {
        reorder_kernel<<<(N_EDGE + 255) / 256, 256, 0, stream>>>(perm, sender, edge_attrs, sid_arr, (float4*)ea_perm);
        tpw_gemm_kernel<<<dim3(128, 4), 512, 0, stream>>>(perm, h3, w_rad4, tpw);
        stream_gather_kernel<<<N_NODES, 256, 0, stream>>>(offs, sid_arr, x, ea_perm, tpw, out);
    } else {
        fused_gather_kernel<<<N_NODES, 512, 0, stream>>>(perm, offs, sender, x, edge_attrs, h3, w_rad4, out);
    }

    out_kernel<<<N_NODES / ONODES, 256, 0, stream>>>(out, w_out);
}

// Round 18
// 359.842 us; speedup vs baseline: 1.1537x; 1.1537x over previous
//
#include <hip/hip_runtime.h>
#include <hip/hip_bf16.h>
#include <math.h>

#define N_NODES 5000
#define N_ELEMS 10
#define C_DIM   128
#define N_EDGE  100000
#define N_BES   8
#define RAD_H   64
#define NL      4
#define SH_DIM  16
#define ONODES  8
#define TPW_ROWS 64

// scales
#define SC_SCALE 0.02795084971874737f    // 1/sqrt(128*10)
#define X_SCALE  0.08838834764831845f    // 1/sqrt(128)
#define R1_SCALE 0.3535533905932738f     // 1/sqrt(8)
#define R_SCALE  0.125f                  // 1/sqrt(64)
#define OUT_SCALE 0.004419417382415922f  // (1/sqrt(128))/20

typedef __attribute__((ext_vector_type(8))) short short8;
typedef __attribute__((ext_vector_type(4))) float f32x4;

__device__ __forceinline__ float silu(float v) { return v / (1.f + __expf(-v)); }
__device__ __forceinline__ unsigned short bf16bits(float v) {
    __hip_bfloat16 h = __float2bfloat16(v);
    return *(unsigned short*)&h;
}

// ---------------- node kernel: sc + x ----------------
__global__ __launch_bounds__(128) void node_kernel(
    const float* __restrict__ node_attrs, const float* __restrict__ node_feats,
    const float* __restrict__ w_skip, const float* __restrict__ w_up,
    float* __restrict__ x, float* __restrict__ sc_out)
{
    int n = blockIdx.x, t = threadIdx.x;
    __shared__ float f[C_DIM];
    __shared__ float at[N_ELEMS];
    f[t] = node_feats[(size_t)n * C_DIM + t];
    if (t < N_ELEMS) at[t] = node_attrs[(size_t)n * N_ELEMS + t];
    __syncthreads();

    float acc = 0.f;
    for (int a = 0; a < N_ELEMS; ++a) {
        float av = at[a];
        if (av != 0.f) {
            const float* wp = w_skip + a * C_DIM + t;
            float s2 = 0.f;
            #pragma unroll 8
            for (int c = 0; c < C_DIM; ++c) s2 += f[c] * wp[(size_t)c * (N_ELEMS * C_DIM)];
            acc += av * s2;
        }
    }
    sc_out[(size_t)n * C_DIM + t] = acc * SC_SCALE;

    float xa = 0.f;
    #pragma unroll 8
    for (int k = 0; k < C_DIM; ++k) xa += f[k] * w_up[k * C_DIM + t];
    x[(size_t)n * C_DIM + t] = xa * X_SCALE;
}

// ---------------- radial MLP layers 1-3 -> h3 ----------------
__global__ __launch_bounds__(256) void radial_kernel(
    const float* __restrict__ edge_feats,
    const float* __restrict__ w1, const float* __restrict__ w2, const float* __restrict__ w3,
    float* __restrict__ h3out)
{
    __shared__ float w1s[N_BES * RAD_H];
    __shared__ float w2s[RAD_H * RAD_H];
    __shared__ float w3s[RAD_H * RAD_H];
    __shared__ float h1s[4][RAD_H];
    __shared__ float h2s[4][RAD_H];
    int t = threadIdx.x;
    for (int i = t; i < N_BES * RAD_H; i += 256) w1s[i] = w1[i];
    for (int i = t; i < RAD_H * RAD_H; i += 256) { w2s[i] = w2[i]; w3s[i] = w3[i]; }
    __syncthreads();
    int sub = t >> 6, j = t & 63;
    for (int e0 = blockIdx.x * 4; e0 < N_EDGE; e0 += gridDim.x * 4) {
        int e = e0 + sub;
        if (e < N_EDGE) {
            const float4* ef = (const float4*)(edge_feats + (size_t)e * N_BES);
            float4 f0 = ef[0], f1 = ef[1];
            float a = f0.x * w1s[0 * RAD_H + j] + f0.y * w1s[1 * RAD_H + j]
                    + f0.z * w1s[2 * RAD_H + j] + f0.w * w1s[3 * RAD_H + j]
                    + f1.x * w1s[4 * RAD_H + j] + f1.y * w1s[5 * RAD_H + j]
                    + f1.z * w1s[6 * RAD_H + j] + f1.w * w1s[7 * RAD_H + j];
            h1s[sub][j] = silu(a * R1_SCALE);
        }
        __syncthreads();
        if (e < N_EDGE) {
            const float4* h4 = (const float4*)h1s[sub];
            float a = 0.f;
            #pragma unroll
            for (int kk = 0; kk < RAD_H / 4; ++kk) {
                float4 h = h4[kk];
                int k = kk * 4;
                a += h.x * w2s[(k + 0) * RAD_H + j] + h.y * w2s[(k + 1) * RAD_H + j]
                   + h.z * w2s[(k + 2) * RAD_H + j] + h.w * w2s[(k + 3) * RAD_H + j];
            }
            h2s[sub][j] = silu(a * R_SCALE);
        }
        __syncthreads();
        if (e < N_EDGE) {
            const float4* h4 = (const float4*)h2s[sub];
            float a = 0.f;
            #pragma unroll
            for (int kk = 0; kk < RAD_H / 4; ++kk) {
                float4 h = h4[kk];
                int k = kk * 4;
                a += h.x * w3s[(k + 0) * RAD_H + j] + h.y * w3s[(k + 1) * RAD_H + j]
                   + h.z * w3s[(k + 2) * RAD_H + j] + h.w * w3s[(k + 3) * RAD_H + j];
            }
            h3out[(size_t)e * RAD_H + j] = silu(a * R_SCALE);
        }
        __syncthreads();
    }
}

// ---------------- CSR build ----------------
__global__ void hist_kernel(const int* __restrict__ recv, int* __restrict__ deg)
{
    int e = blockIdx.x * 256 + threadIdx.x;
    if (e < N_EDGE) atomicAdd(&deg[recv[e]], 1);
}

__global__ __launch_bounds__(256) void scan_kernel(const int* __restrict__ deg, int* __restrict__ offs)
{
    __shared__ int sums[256];
    int t = threadIdx.x;
    int base = t * 20;
    int loc[20]; int s = 0;
    #pragma unroll
    for (int i = 0; i < 20; ++i) { int idx = base + i; int v = (idx < N_NODES) ? deg[idx] : 0; loc[i] = s; s += v; }
    sums[t] = s; __syncthreads();
    for (int off = 1; off < 256; off <<= 1) {
        int v = (t >= off) ? sums[t - off] : 0;
        __syncthreads();
        sums[t] += v;
        __syncthreads();
    }
    int ex = (t == 0) ? 0 : sums[t - 1];
    #pragma unroll
    for (int i = 0; i < 20; ++i) { int idx = base + i; if (idx < N_NODES) offs[idx] = ex + loc[i]; }
    if (t == 255) offs[N_NODES] = sums[255];
}

__global__ void scatter_kernel(const int* __restrict__ recv, const int* __restrict__ offs,
                               int* __restrict__ cursor, int* __restrict__ perm)
{
    int e = blockIdx.x * 256 + threadIdx.x;
    if (e < N_EDGE) {
        int r = recv[e];
        int pos = atomicAdd(&cursor[r], 1);
        perm[offs[r] + pos] = e;
    }
}

// ---------------- reorder: sid_arr[idx]=sender[perm[idx]], ea_perm[idx]=edge_attrs[perm[idx]] ----------------
__global__ void reorder_kernel(const int* __restrict__ perm, const int* __restrict__ sender,
                               const float* __restrict__ edge_attrs,
                               int* __restrict__ sid_arr, float4* __restrict__ ea_perm4)
{
    int idx = blockIdx.x * 256 + threadIdx.x;
    if (idx < N_EDGE) {
        int e = perm[idx];
        sid_arr[idx] = sender[e];
        const float4* src = (const float4*)(edge_attrs + (size_t)e * SH_DIM);
        float4* dst = ea_perm4 + (size_t)idx * 4;
        dst[0] = src[0]; dst[1] = src[1]; dst[2] = src[2]; dst[3] = src[3];
    }
}

// ---------------- tpw GEMM via MFMA (bf16): tpw[i,:] = h3[perm[i],:] @ w4*R_SCALE ----------------
// v3: matrix cores. Round-17 lesson: VALU path has ~71us issue floor; MFMA
// shrinks compute to ~2us -> staging/write-bound. 64-edge x 128-col tile,
// 4 waves x (8 n-frags x 2 k-steps) of mfma_f32_16x16x32_bf16.
// A: m=lane&15, k=(lane>>4)*8+j ; B: n=lane&15, same k ; D: col=lane&15,
// row=(lane>>4)*4+reg (m89-verified).
__global__ __launch_bounds__(256, 2) void tpw_gemm_kernel(
    const int* __restrict__ perm, const float* __restrict__ h3,
    const float* __restrict__ w4, __hip_bfloat16* __restrict__ tpw)
{
    __shared__ unsigned short As[64 * 72];    // [row][k] pad+8  (9.2 KB)
    __shared__ unsigned short Bp[128 * 72];   // [n][k]  pad+8  (18.4 KB)
    __shared__ unsigned short epi[64 * 136];  // [row][n] pad+8 (17.4 KB)
    int l = blockIdx.y, t = threadIdx.x;
    int lane = t & 63, wid = t >> 6;

    // stage B panel (w4 slice, R_SCALE folded), transposed to [n][k]
    for (int idx = t; idx < RAD_H * C_DIM; idx += 256) {
        int k = idx >> 7, n = idx & 127;
        Bp[n * 72 + k] = bf16bits(w4[k * (NL * C_DIM) + l * C_DIM + n] * R_SCALE);
    }
    __syncthreads();

    // load all 16 B fragments into registers (static indexing)
    short8 bfr[2][8];
    #pragma unroll
    for (int s = 0; s < 2; ++s)
        #pragma unroll
        for (int f = 0; f < 8; ++f)
            bfr[s][f] = *(const short8*)&Bp[(f * 16 + (lane & 15)) * 72 + s * 32 + (lane >> 4) * 8];

    const int ntiles = (N_EDGE + TPW_ROWS - 1) / TPW_ROWS;   // 1563
    for (int tile = blockIdx.x; tile < ntiles; tile += gridDim.x) {
        int i0 = tile * TPW_ROWS;
        // stage A: 64 rows of h3[perm[i]] -> bf16 [row][k]
        {
            int r = t >> 2, q = t & 3;
            int e = perm[min(i0 + r, N_EDGE - 1)];
            const float4* src = (const float4*)(h3 + (size_t)e * RAD_H + q * 16);
            unsigned short tmp[16];
            #pragma unroll
            for (int v = 0; v < 4; ++v) {
                float4 fv = src[v];
                tmp[v * 4 + 0] = bf16bits(fv.x);
                tmp[v * 4 + 1] = bf16bits(fv.y);
                tmp[v * 4 + 2] = bf16bits(fv.z);
                tmp[v * 4 + 3] = bf16bits(fv.w);
            }
            *(short8*)&As[r * 72 + q * 16]     = *(short8*)&tmp[0];
            *(short8*)&As[r * 72 + q * 16 + 8] = *(short8*)&tmp[8];
        }
        __syncthreads();    // As ready; prev copy-out done

        f32x4 acc[8] = {};
        #pragma unroll
        for (int s = 0; s < 2; ++s) {
            short8 a = *(const short8*)&As[(wid * 16 + (lane & 15)) * 72 + s * 32 + (lane >> 4) * 8];
            #pragma unroll
            for (int f = 0; f < 8; ++f)
                acc[f] = __builtin_amdgcn_mfma_f32_16x16x32_bf16(a, bfr[s][f], acc[f], 0, 0, 0);
        }
        // epilogue: acc -> epi LDS (row-major) for coalesced global stores
        #pragma unroll
        for (int f = 0; f < 8; ++f)
            #pragma unroll
            for (int r = 0; r < 4; ++r)
                epi[(wid * 16 + (lane >> 4) * 4 + r) * 136 + f * 16 + (lane & 15)] = bf16bits(acc[f][r]);
        __syncthreads();    // epi ready; all As reads done

        {
            int row = t >> 2, q = t & 3;
            if (i0 + row < N_EDGE) {
                unsigned short* dst = (unsigned short*)tpw + (size_t)(i0 + row) * (NL * C_DIM) + l * C_DIM + q * 32;
                #pragma unroll
                for (int v = 0; v < 4; ++v)
                    *(short8*)(dst + v * 8) = *(const short8*)&epi[row * 136 + q * 32 + v * 8];
            }
        }
    }
}

// ---------------- stream gather v3: 256 thr (l=t>>6 wave-uniform, 2 c's/thread) ----------------
__global__ __launch_bounds__(256, 4) void stream_gather_kernel(
    const int* __restrict__ offs, const int* __restrict__ sid_arr,
    const float* __restrict__ x, const float* __restrict__ ea_perm,
    const __hip_bfloat16* __restrict__ tpw, float* __restrict__ msg)
{
    int n = blockIdx.x, t = threadIdx.x;
    int cq = t & 63, l = t >> 6;          // l wave-uniform; c = cq*2, cq*2+1
    int c0 = cq * 2;
    float acc[7][2] = {};
    int nm = 2 * l + 1;
    int start = offs[n], end = offs[n + 1];

    for (int base = start; base < end; base += 4) {
        int idxb[4], sidb[4];
        #pragma unroll
        for (int j = 0; j < 4; ++j) idxb[j] = min(base + j, end - 1);
        #pragma unroll
        for (int j = 0; j < 4; ++j) sidb[j] = sid_arr[idxb[j]];   // wave-uniform -> s_load

        unsigned int tpb[4];
        float2 xv[4];
        #pragma unroll
        for (int j = 0; j < 4; ++j)
            tpb[j] = *(const unsigned int*)((const unsigned short*)tpw + (size_t)idxb[j] * (NL * C_DIM) + l * C_DIM + c0);
        #pragma unroll
        for (int j = 0; j < 4; ++j)
            xv[j] = *(const float2*)(x + (size_t)sidb[j] * C_DIM + c0);
        asm volatile("" : "+v"(tpb[0]), "+v"(tpb[1]), "+v"(tpb[2]), "+v"(tpb[3]),
                          "+v"(xv[0].x), "+v"(xv[0].y), "+v"(xv[1].x), "+v"(xv[1].y),
                          "+v"(xv[2].x), "+v"(xv[2].y), "+v"(xv[3].x), "+v"(xv[3].y));

        #pragma unroll
        for (int j = 0; j < 4; ++j) {
            unsigned int lo = (tpb[j] & 0xFFFFu) << 16;
            unsigned int hi = tpb[j] & 0xFFFF0000u;
            float tp0 = __uint_as_float(lo);
            float tp1 = __uint_as_float(hi);
            bool valid = (base + j < end);
            float xt0 = valid ? tp0 * xv[j].x : 0.f;
            float xt1 = valid ? tp1 * xv[j].y : 0.f;
            const float* ear = ea_perm + (size_t)idxb[j] * SH_DIM + l * l;   // wave-uniform
            #pragma unroll
            for (int m = 0; m < 7; ++m)
                if (m < nm) { acc[m][0] += ear[m] * xt0; acc[m][1] += ear[m] * xt1; }
        }
    }
    float* mout = msg + (size_t)n * (SH_DIM * C_DIM) + (size_t)(l * l) * C_DIM + c0;
    #pragma unroll
    for (int m = 0; m < 7; ++m)
        if (m < nm) *(float2*)(mout + (size_t)m * C_DIM) = make_float2(acc[m][0], acc[m][1]);
}

// ---------------- fallback fused gather (round-7, e-indexed) ----------------
__global__ __launch_bounds__(512, 4) void fused_gather_kernel(
    const int* __restrict__ perm, const int* __restrict__ offs,
    const int* __restrict__ sender, const float* __restrict__ x,
    const float* __restrict__ edge_attrs, const float* __restrict__ h3,
    const float* __restrict__ w4, float* __restrict__ msg)
{
    int n = blockIdx.x, t = threadIdx.x;
    int c = t & 127, l = t >> 7;
    float wc[RAD_H];
    #pragma unroll
    for (int k = 0; k < RAD_H; ++k)
        wc[k] = w4[k * (NL * C_DIM) + l * C_DIM + c];

    float acc[7] = {0.f, 0.f, 0.f, 0.f, 0.f, 0.f, 0.f};
    int nm = 2 * l + 1;
    int start = offs[n], end = offs[n + 1];
    if (start < end) {
        int e = __builtin_amdgcn_readfirstlane(perm[start]);
        int s = __builtin_amdgcn_readfirstlane(sender[e]);
        for (int idx = start; idx < end; ++idx) {
            #pragma unroll
            for (int k = 0; k < RAD_H; k += 8)
                asm volatile("" : "+v"(wc[k]), "+v"(wc[k+1]), "+v"(wc[k+2]), "+v"(wc[k+3]),
                                  "+v"(wc[k+4]), "+v"(wc[k+5]), "+v"(wc[k+6]), "+v"(wc[k+7]));
            int e_cur = e, s_cur = s;
            if (idx + 1 < end) {
                e = __builtin_amdgcn_readfirstlane(perm[idx + 1]);
                s = __builtin_amdgcn_readfirstlane(sender[e]);
            }
            const float* h3r = h3 + (size_t)e_cur * RAD_H;
            float xv = x[(size_t)s_cur * C_DIM + c];
            float tp0 = 0.f, tp1 = 0.f, tp2 = 0.f, tp3 = 0.f;
            #pragma unroll
            for (int q = 0; q < RAD_H / 4; ++q) {
                tp0 += h3r[4 * q + 0] * wc[4 * q + 0];
                tp1 += h3r[4 * q + 1] * wc[4 * q + 1];
                tp2 += h3r[4 * q + 2] * wc[4 * q + 2];
                tp3 += h3r[4 * q + 3] * wc[4 * q + 3];
            }
            float tp = (tp0 + tp1) + (tp2 + tp3);
            float xt = xv * (tp * R_SCALE);
            const float* ear = edge_attrs + (size_t)e_cur * SH_DIM + l * l;
            #pragma unroll
            for (int j = 0; j < 7; ++j)
                if (j < nm) acc[j] += ear[j] * xt;
        }
    }
    float* mout = msg + (size_t)n * (SH_DIM * C_DIM) + (size_t)(l * l) * C_DIM + c;
    #pragma unroll
    for (int j = 0; j < 7; ++j)
        if (j < nm) mout[(size_t)j * C_DIM] = acc[j];
}

// ---------------- out[n,m,d] = sum_c msg[n,m,c]*w_out[l(m),c,d]  (in place on d_out) ----------------
__global__ __launch_bounds__(256, 4) void out_kernel(
    float* __restrict__ out, const float* __restrict__ w_out)
{
    __shared__ float wlds[64 * C_DIM];        // 32 KB half-k panel
    int nb = blockIdx.x * ONODES, t = threadIdx.x;
    int dq = t & 31, rg = t >> 5;
    int d0 = dq * 4;
    #pragma unroll
    for (int l = 0; l < 4; ++l) {
        const int ms = l * l, cnt = 2 * l + 1;
        const int ntiles = ONODES * cnt / 4;  // 2,6,10,14
        float acc[2][4][4] = {};
        #pragma unroll
        for (int half = 0; half < 2; ++half) {
            const int k0h = half * 64;
            __syncthreads();
            {
                const float4* src = (const float4*)(w_out + ((size_t)l * C_DIM + k0h) * C_DIM);
                float4* dst = (float4*)wlds;
                for (int i = t; i < 64 * C_DIM / 4; i += 256) dst[i] = src[i];
            }
            __syncthreads();
            #pragma unroll
            for (int slot = 0; slot < 2; ++slot) {
                int ti = rg + slot * 8;
                if (ti < ntiles) {
                    int r0 = ti * 4;
                    const float* mrow[4];
                    #pragma unroll
                    for (int i = 0; i < 4; ++i) {
                        int r = r0 + i;
                        int node = r / cnt, mm = ms + r % cnt;
                        mrow[i] = out + ((size_t)(nb + node) * SH_DIM + mm) * C_DIM + k0h;
                    }
                    #pragma unroll 2
                    for (int k0 = 0; k0 < 64; k0 += 4) {
                        float4 b0 = *(const float4*)&wlds[(k0 + 0) * C_DIM + d0];
                        float4 b1 = *(const float4*)&wlds[(k0 + 1) * C_DIM + d0];
                        float4 b2 = *(const float4*)&wlds[(k0 + 2) * C_DIM + d0];
                        float4 b3 = *(const float4*)&wlds[(k0 + 3) * C_DIM + d0];
                        #pragma unroll
                        for (int i = 0; i < 4; ++i) {
                            float4 a = *(const float4*)(mrow[i] + k0);
                            acc[slot][i][0] += a.x * b0.x + a.y * b1.x + a.z * b2.x + a.w * b3.x;
                            acc[slot][i][1] += a.x * b0.y + a.y * b1.y + a.z * b2.y + a.w * b3.y;
                            acc[slot][i][2] += a.x * b0.z + a.y * b1.z + a.z * b2.z + a.w * b3.z;
                            acc[slot][i][3] += a.x * b0.w + a.y * b1.w + a.z * b2.w + a.w * b3.w;
                        }
                    }
                }
            }
        }
        #pragma unroll
        for (int slot = 0; slot < 2; ++slot) {
            int ti = rg + slot * 8;
            if (ti < ntiles) {
                int r0 = ti * 4;
                #pragma unroll
                for (int i = 0; i < 4; ++i) {
                    int r = r0 + i;
                    int node = r / cnt, mm = ms + r % cnt;
                    float4 r4 = make_float4(acc[slot][i][0] * OUT_SCALE, acc[slot][i][1] * OUT_SCALE,
                                            acc[slot][i][2] * OUT_SCALE, acc[slot][i][3] * OUT_SCALE);
                    *(float4*)(out + ((size_t)(nb + node) * SH_DIM + mm) * C_DIM + d0) = r4;
                }
            }
        }
    }
}

extern "C" void kernel_launch(void* const* d_in, const int* in_sizes, int n_in,
                              void* d_out, int out_size, void* d_ws, size_t ws_size,
                              hipStream_t stream)
{
    const float* node_attrs = (const float*)d_in[0];
    const float* node_feats = (const float*)d_in[1];
    const float* edge_attrs = (const float*)d_in[2];
    const float* edge_feats = (const float*)d_in[3];
    const int*   edge_index = (const int*)d_in[4];
    const float* w_up   = (const float*)d_in[5];
    const float* w_rad1 = (const float*)d_in[6];
    const float* w_rad2 = (const float*)d_in[7];
    const float* w_rad3 = (const float*)d_in[8];
    const float* w_rad4 = (const float*)d_in[9];
    const float* w_skip = (const float*)d_in[10];
    const float* w_out  = (const float*)d_in[11];
    const int* sender = edge_index;
    const int* recv   = edge_index + N_EDGE;

    float* out = (float*)d_out;                                 // msg staged here, then in-place
    float* sc  = out + (size_t)N_NODES * SH_DIM * C_DIM;

    // workspace layout (ws >= 233.4 MB proven; this needs ~138 MB)
    float* x   = (float*)d_ws;
    float* h3  = x + (size_t)N_NODES * C_DIM;
    int* deg    = (int*)(h3 + (size_t)N_EDGE * RAD_H);
    int* cursor = deg + 5120;
    int* offs   = cursor + 5120;
    int* perm   = offs + 5124;
    __hip_bfloat16* tpw = (__hip_bfloat16*)(perm + N_EDGE);
    int* sid_arr = (int*)(tpw + (size_t)N_EDGE * NL * C_DIM);
    float* ea_perm = (float*)(sid_arr + N_EDGE);
    size_t need = (size_t)((char*)(ea_perm + (size_t)N_EDGE * SH_DIM) - (char*)d_ws);
    int mode = (ws_size >= need) ? 1 : 0;

    hipMemsetAsync(deg, 0, 2 * 5120 * sizeof(int), stream);

    node_kernel<<<N_NODES, 128, 0, stream>>>(node_attrs, node_feats, w_skip, w_up, x, sc);
    radial_kernel<<<1024, 256, 0, stream>>>(edge_feats, w_rad1, w_rad2, w_rad3, h3);

    hist_kernel<<<(N_EDGE + 255) / 256, 256, 0, stream>>>(recv, deg);
    scan_kernel<<<1, 256, 0, stream>>>(deg, offs);
    scatter_kernel<<<(N_EDGE + 255) / 256, 256, 0, stream>>>(recv, offs, cursor, perm);

    if (mode == 1) {
        reorder_kernel<<<(N_EDGE + 255) / 256, 256, 0, stream>>>(perm, sender, edge_attrs, sid_arr, (float4*)ea_perm);
        tpw_gemm_kernel<<<dim3(391, 4), 256, 0, stream>>>(perm, h3, w_rad4, tpw);
        stream_gather_kernel<<<N_NODES, 256, 0, stream>>>(offs, sid_arr, x, ea_perm, tpw, out);
    } else {
        fused_gather_kernel<<<N_NODES, 512, 0, stream>>>(perm, offs, sender, x, edge_attrs, h3, w_rad4, out);
    }

    out_kernel<<<N_NODES / ONODES, 256, 0, stream>>>(out, w_out);
}